// Round 11
// baseline (2032.149 us; speedup 1.0000x reference)
//
#include <hip/hip_runtime.h>
#include <hip/hip_bf16.h>
#include <stdint.h>

// Problem constants (reference: LoRA adapter forward)
#define TOKENS   8192
#define DIM      4096
#define DIM_OUT  4096
#define LORA_R   16
#define LORA_SCALE 2.0f

typedef __bf16 bf16_t;
typedef __attribute__((ext_vector_type(8))) __bf16 bfrag;   // 8 bf16 = 4 VGPR (MFMA A/B frag)
typedef __attribute__((ext_vector_type(4))) float f32x4;    // MFMA C/D frag

// ---------------------------------------------------------------------------
// async global->LDS, 16B per lane (global_load_lds_dwordx4)
// ---------------------------------------------------------------------------
__device__ __forceinline__ void gload_lds16(const bf16_t* gsrc, bf16_t* ldst) {
    __builtin_amdgcn_global_load_lds(
        (const __attribute__((address_space(1))) uint32_t*)(const void*)gsrc,
        (__attribute__((address_space(3))) uint32_t*)(void*)ldst,
        16, 0, 0);
}

// ---------------------------------------------------------------------------
// Kernel 1: fused prep (R4/R6-validated form).
// Blocks [0,2048): cast x fp32->bf16.  Blocks [2048,4096): Weff.
// ---------------------------------------------------------------------------
#define CAST_BLOCKS 2048
__global__ void prep_kernel(const float* __restrict__ x, bf16_t* __restrict__ xb,
                            const float* __restrict__ W, const float* __restrict__ A,
                            const float* __restrict__ B, bf16_t* __restrict__ Wt) {
    if (blockIdx.x < CAST_BLOCKS) {
        const int total = TOKENS * DIM / 8;
        for (int i = blockIdx.x * blockDim.x + threadIdx.x; i < total;
             i += CAST_BLOCKS * 256) {
            const float4* p = reinterpret_cast<const float4*>(x + (size_t)i * 8);
            float4 v0 = p[0], v1 = p[1];
            union { bf16_t o[8]; uint4 u; } pk;
            pk.o[0] = (bf16_t)v0.x; pk.o[1] = (bf16_t)v0.y;
            pk.o[2] = (bf16_t)v0.z; pk.o[3] = (bf16_t)v0.w;
            pk.o[4] = (bf16_t)v1.x; pk.o[5] = (bf16_t)v1.y;
            pk.o[6] = (bf16_t)v1.z; pk.o[7] = (bf16_t)v1.w;
            *reinterpret_cast<uint4*>(xb + (size_t)i * 8) = pk.u;
        }
    } else {
        int idx = (blockIdx.x - CAST_BLOCKS) * blockDim.x + threadIdx.x;
        int k0 = (idx & 511) << 3;          // 512 k-groups of 8
        int n0 = (idx >> 9) << 2;           // 1024 n-groups of 4

        float bn[4][16];
#pragma unroll
        for (int r = 0; r < 16; ++r) {
            float4 bv = *reinterpret_cast<const float4*>(B + (size_t)r * DIM_OUT + n0);
            bn[0][r] = bv.x; bn[1][r] = bv.y; bn[2][r] = bv.z; bn[3][r] = bv.w;
        }
        float ab[4][8];
#pragma unroll
        for (int j = 0; j < 8; ++j) {
            const float4* ap = reinterpret_cast<const float4*>(A + (size_t)(k0 + j) * LORA_R);
            float4 a0 = ap[0], a1 = ap[1], a2 = ap[2], a3 = ap[3];
            float av[16] = {a0.x,a0.y,a0.z,a0.w,a1.x,a1.y,a1.z,a1.w,
                            a2.x,a2.y,a2.z,a2.w,a3.x,a3.y,a3.z,a3.w};
#pragma unroll
            for (int n = 0; n < 4; ++n) {
                float s = 0.f;
#pragma unroll
                for (int r = 0; r < 16; ++r) s += av[r] * bn[n][r];
                ab[n][j] = s;
            }
        }
#pragma unroll
        for (int n = 0; n < 4; ++n) {
            const float4* wp = reinterpret_cast<const float4*>(W + (size_t)(n0 + n) * DIM + k0);
            float4 w0 = wp[0], w1 = wp[1];
            float wv[8] = {w0.x,w0.y,w0.z,w0.w,w1.x,w1.y,w1.z,w1.w};
            union { bf16_t o[8]; uint4 u; } pk;
#pragma unroll
            for (int j = 0; j < 8; ++j) pk.o[j] = (bf16_t)(wv[j] + LORA_SCALE * ab[n][j]);
            *reinterpret_cast<uint4*>(Wt + (size_t)(n0 + n) * DIM + k0) = pk.u;
        }
    }
}

// ---------------------------------------------------------------------------
// Kernel 2: 256x256 GEMM, BK=32, 4-buffer ring (R9-validated staging/swizzle),
// ONE change vs R9: wave ANTI-PHASING.  Waves split into G0/G1; G1 carries a
// half-tile of operands in REGISTERS across each barrier and issues its
// 16-MFMA burst while G0 waves are in their read burst -> LDS pipe and
// matrix pipe co-run instead of alternating (measured R2-R9: wall = MFMA
// cyc + LDS cyc, i.e. serial).
// All LDS reads stay inside the window that published the tile (4-buffer
// ring: buf[w&3] written in window w-2, read in window w, rewritten at
// w+2 -> >=1 barrier between every read and overwrite; only registers
// cross barriers).  vmcnt(4) per window keeps staging loads in flight.
// G0/G1 assignment (wid&1)^((wid>>2)&1): one of each per SIMD under either
// round-robin or chunked wave->SIMD mapping.
// ---------------------------------------------------------------------------
#define BM 256
#define BN 256
#define BK 32
#define MB_BLKS (TOKENS / BM)    // 32
#define NB_BLKS (DIM_OUT / BN)   // 16
#define NT      (DIM / BK)       // 128 K-tiles

#define SB0() __builtin_amdgcn_sched_barrier(0)
#define VMWAIT_(n) asm volatile("s_waitcnt vmcnt(" #n ")" ::: "memory")
#define VMWAIT(n) VMWAIT_(n)

__global__ __launch_bounds__(512, 2) void gemm_kernel(
    const bf16_t* __restrict__ Xb, const bf16_t* __restrict__ Wt,
    const float* __restrict__ bias, float* __restrict__ C)
{
    __shared__ __align__(16) bf16_t sA[4][BM][BK];   // 64 KiB
    __shared__ __align__(16) bf16_t sB[4][BN][BK];   // 64 KiB

    const int nwg = MB_BLKS * NB_BLKS;               // 512, %8==0 -> bijective
    int bid = blockIdx.x;
    int swz = (bid & 7) * (nwg >> 3) + (bid >> 3);   // XCD-aware remap
    int bm = swz / NB_BLKS;
    int bn = swz % NB_BLKS;

    const int tid  = threadIdx.x;
    const int lane = tid & 63;
    const int wid  = tid >> 6;       // 0..7
    const int wr   = wid >> 2;       // 0..1  (M half: 128 rows)
    const int wc   = wid & 3;        // 0..3  (N quarter: 64 cols)
    const bool g0  = (((wid & 1) ^ ((wid >> 2) & 1)) == 0);  // anti-phase split

    // ---- staging constants (linear LDS dest, pre-swizzled global src) ----
    const int srow = tid >> 2;                       // 0..127
    const int slin = (tid & 3) * 8;                  // linear col slot (elems)
    const int koff = (((tid & 3) ^ ((tid >> 3) & 3)) * 8); // swizzled src col
    const bf16_t* Ag = Xb + (size_t)(bm * BM + srow) * DIM + koff;
    const bf16_t* Bg = Wt + (size_t)(bn * BN + srow) * DIM + koff;

#define STAGE_A(sb, kt) do { \
    const bf16_t* s_ = Ag + (size_t)(kt) * BK; \
    gload_lds16(s_,                     &sA[sb][srow][slin]); \
    gload_lds16(s_ + (size_t)128 * DIM, &sA[sb][128 + srow][slin]); \
} while (0)

#define STAGE_B(sb, kt) do { \
    const bf16_t* s_ = Bg + (size_t)(kt) * BK; \
    gload_lds16(s_,                     &sB[sb][srow][slin]); \
    gload_lds16(s_ + (size_t)128 * DIM, &sB[sb][128 + srow][slin]); \
} while (0)

    // ---- fragment-read constants (R9-verified swizzle, 0 conflicts) ----
    const int r15  = lane & 15;
    const int cK   = (((lane >> 4) ^ ((r15 >> 1) & 3))) * 8;  // swizzled col
    const int arow0 = wr * 128 + r15;                // + m*16
    const int brow0 = wc * 64  + r15;                // + n*16

    f32x4 acc[8][4] = {};
    // G0 operands
    bfrag b0[4], aT2[4];
    // shared transient + G1 ping-pong carried sets
    bfrag aT[4], bX[4], bY[4], aX[4], aY[4];

#define READ_B4(rb, bD) do { \
    _Pragma("unroll") \
    for (int n_ = 0; n_ < 4; ++n_) \
        bD[n_] = *reinterpret_cast<const bfrag*>(&sB[rb][brow0 + n_ * 16][cK]); \
} while (0)

#define READ_A4H(rb, aD, mb) do { \
    _Pragma("unroll") \
    for (int m_ = 0; m_ < 4; ++m_) \
        aD[m_] = *reinterpret_cast<const bfrag*>(&sA[rb][arow0 + (mb + m_) * 16][cK]); \
} while (0)

// 16 MFMA: m-blocks mb..mb+3 x n 0..3
#define MFMA_H(Af, Bf, mb) do { \
    __builtin_amdgcn_s_setprio(1); \
    _Pragma("unroll") \
    for (int m_ = 0; m_ < 4; ++m_) \
    _Pragma("unroll") \
    for (int n_ = 0; n_ < 4; ++n_) \
        acc[mb + m_][n_] = __builtin_amdgcn_mfma_f32_16x16x32_bf16( \
            Af[m_], Bf[n_], acc[mb + m_][n_], 0, 0, 0); \
    __builtin_amdgcn_s_setprio(0); \
} while (0)

// One window (tile w, read buf rb=w&3).  S: stage tile ktn -> buf sb.
// G0: read h1, mfma h1, read h2, mfma h2   (all of tile w)
// G1: mfma h2(prev, regs bP/aP) ; read h1 -> bC/aT ; mfma h1 ; read h2 -> aC
#define WIN(rb, sb, ktn, S, VM, LEAD, bP, aP, bC, aC) do { \
    if (S) { STAGE_A(sb, ktn); STAGE_B(sb, ktn); } \
    if (g0) { \
        READ_B4(rb, b0); READ_A4H(rb, aT, 0); \
        MFMA_H(aT, b0, 0); \
        READ_A4H(rb, aT2, 4); \
        MFMA_H(aT2, b0, 4); \
    } else { \
        if (LEAD) MFMA_H(aP, bP, 4); \
        READ_B4(rb, bC); READ_A4H(rb, aT, 0); \
        MFMA_H(aT, bC, 0); \
        READ_A4H(rb, aC, 4); \
    } \
    SB0(); VMWAIT(VM); __builtin_amdgcn_s_barrier(); SB0(); \
} while (0)

    // ---- prologue: tiles 0,1 -> bufs 0,1 ----
    STAGE_A(0, 0); STAGE_B(0, 0);
    STAGE_A(1, 1); STAGE_B(1, 1);
    VMWAIT(4);          // tile 0 landed; tile 1's 4 loads stay in flight
    __builtin_amdgcn_s_barrier(); SB0();

    // ---- w0 (cur set X, no lead) ----
    WIN(0, 2, 2, true, 4, false, bX, aX, bX, aX);

    // ---- main loop: w=1..124 (31 iters x 4), staging w+2 ----
    for (int it = 0; it < 31; ++it) {
        int t4 = 4 * it;
        WIN(1, 3, t4 + 3, true, 4, true, bX, aX, bY, aY);
        WIN(2, 0, t4 + 4, true, 4, true, bY, aY, bX, aX);
        WIN(3, 1, t4 + 5, true, 4, true, bX, aX, bY, aY);
        WIN(0, 2, t4 + 6, true, 4, true, bY, aY, bX, aX);
    }
    // ---- peeled w125..w127 ----
    WIN(1, 3, 127, true,  4, true, bX, aX, bY, aY);   // w125 stages tile 127
    WIN(2, 0, 0,   false, 0, true, bY, aY, bX, aX);   // w126: drain
    WIN(3, 0, 0,   false, 0, true, bX, aX, bY, aY);   // w127
    if (!g0) MFMA_H(aY, bY, 4);                        // h2 of tile 127

    // ---- epilogue: D layout row=(lane>>4)*4+j, col=lane&15 ----
    int row0 = bm * BM + wr * 128 + (lane >> 4) * 4;
    int col0 = bn * BN + wc * 64 + r15;
#pragma unroll
    for (int n = 0; n < 4; ++n) {
        int c = col0 + n * 16;
        float bv = bias[c];
#pragma unroll
        for (int m = 0; m < 8; ++m) {
            int r = row0 + m * 16;
#pragma unroll
            for (int j = 0; j < 4; ++j)
                C[(size_t)(r + j) * DIM_OUT + c] = acc[m][n][j] + bv;
        }
    }
}

// ---------------------------------------------------------------------------
extern "C" void kernel_launch(void* const* d_in, const int* in_sizes, int n_in,
                              void* d_out, int out_size, void* d_ws, size_t ws_size,
                              hipStream_t stream) {
    const float* x = (const float*)d_in[0];
    const float* A = (const float*)d_in[1];
    const float* B = (const float*)d_in[2];
    const float* W = (const float*)d_in[3];
    const float* b = (const float*)d_in[4];
    float* out = (float*)d_out;

    // workspace: xb (8192*4096 bf16 = 64MB) | Wt (4096*4096 bf16 = 32MB)
    bf16_t* xb = (bf16_t*)d_ws;
    bf16_t* Wt = (bf16_t*)((char*)d_ws + (size_t)TOKENS * DIM * 2);

    prep_kernel<<<CAST_BLOCKS + 2048, 256, 0, stream>>>(x, xb, W, A, B, Wt);
    gemm_kernel<<<MB_BLKS * NB_BLKS, 512, 0, stream>>>(xb, Wt, b, out);
}

// Round 12
// 327.650 us; speedup vs baseline: 6.2022x; 6.2022x over previous
//
#include <hip/hip_runtime.h>
#include <hip/hip_bf16.h>
#include <stdint.h>

// Problem constants (reference: LoRA adapter forward)
#define TOKENS   8192
#define DIM      4096
#define DIM_OUT  4096
#define LORA_R   16
#define LORA_SCALE 2.0f

typedef __bf16 bf16_t;
typedef __attribute__((ext_vector_type(8))) __bf16 bfrag;   // 8 bf16 = 4 VGPR (MFMA A/B frag)
typedef __attribute__((ext_vector_type(4))) float f32x4;    // MFMA C/D frag

// ---------------------------------------------------------------------------
// async global->LDS, 16B per lane (global_load_lds_dwordx4)
// ---------------------------------------------------------------------------
__device__ __forceinline__ void gload_lds16(const bf16_t* gsrc, bf16_t* ldst) {
    __builtin_amdgcn_global_load_lds(
        (const __attribute__((address_space(1))) uint32_t*)(const void*)gsrc,
        (__attribute__((address_space(3))) uint32_t*)(void*)ldst,
        16, 0, 0);
}

// ---------------------------------------------------------------------------
// Kernel 1: fused prep (R4/R6-validated form).
// Blocks [0,2048): cast x fp32->bf16.  Blocks [2048,4096): Weff.
// ---------------------------------------------------------------------------
#define CAST_BLOCKS 2048
__global__ void prep_kernel(const float* __restrict__ x, bf16_t* __restrict__ xb,
                            const float* __restrict__ W, const float* __restrict__ A,
                            const float* __restrict__ B, bf16_t* __restrict__ Wt) {
    if (blockIdx.x < CAST_BLOCKS) {
        const int total = TOKENS * DIM / 8;
        for (int i = blockIdx.x * blockDim.x + threadIdx.x; i < total;
             i += CAST_BLOCKS * 256) {
            const float4* p = reinterpret_cast<const float4*>(x + (size_t)i * 8);
            float4 v0 = p[0], v1 = p[1];
            union { bf16_t o[8]; uint4 u; } pk;
            pk.o[0] = (bf16_t)v0.x; pk.o[1] = (bf16_t)v0.y;
            pk.o[2] = (bf16_t)v0.z; pk.o[3] = (bf16_t)v0.w;
            pk.o[4] = (bf16_t)v1.x; pk.o[5] = (bf16_t)v1.y;
            pk.o[6] = (bf16_t)v1.z; pk.o[7] = (bf16_t)v1.w;
            *reinterpret_cast<uint4*>(xb + (size_t)i * 8) = pk.u;
        }
    } else {
        int idx = (blockIdx.x - CAST_BLOCKS) * blockDim.x + threadIdx.x;
        int k0 = (idx & 511) << 3;          // 512 k-groups of 8
        int n0 = (idx >> 9) << 2;           // 1024 n-groups of 4

        float bn[4][16];
#pragma unroll
        for (int r = 0; r < 16; ++r) {
            float4 bv = *reinterpret_cast<const float4*>(B + (size_t)r * DIM_OUT + n0);
            bn[0][r] = bv.x; bn[1][r] = bv.y; bn[2][r] = bv.z; bn[3][r] = bv.w;
        }
        float ab[4][8];
#pragma unroll
        for (int j = 0; j < 8; ++j) {
            const float4* ap = reinterpret_cast<const float4*>(A + (size_t)(k0 + j) * LORA_R);
            float4 a0 = ap[0], a1 = ap[1], a2 = ap[2], a3 = ap[3];
            float av[16] = {a0.x,a0.y,a0.z,a0.w,a1.x,a1.y,a1.z,a1.w,
                            a2.x,a2.y,a2.z,a2.w,a3.x,a3.y,a3.z,a3.w};
#pragma unroll
            for (int n = 0; n < 4; ++n) {
                float s = 0.f;
#pragma unroll
                for (int r = 0; r < 16; ++r) s += av[r] * bn[n][r];
                ab[n][j] = s;
            }
        }
#pragma unroll
        for (int n = 0; n < 4; ++n) {
            const float4* wp = reinterpret_cast<const float4*>(W + (size_t)(n0 + n) * DIM + k0);
            float4 w0 = wp[0], w1 = wp[1];
            float wv[8] = {w0.x,w0.y,w0.z,w0.w,w1.x,w1.y,w1.z,w1.w};
            union { bf16_t o[8]; uint4 u; } pk;
#pragma unroll
            for (int j = 0; j < 8; ++j) pk.o[j] = (bf16_t)(wv[j] + LORA_SCALE * ab[n][j]);
            *reinterpret_cast<uint4*>(Wt + (size_t)(n0 + n) * DIM + k0) = pk.u;
        }
    }
}

// ---------------------------------------------------------------------------
// Kernel 2: 256x256 GEMM — R6's validated 3-interval snake schedule (257us,
// 47% MfmaUtil), ONE change: XCD-local 2-D block mapping for L3-traffic cut.
//   xcd = bid&7; j = bid>>3; q = j>>5; r = j&31;
//   bm = xcd*4 + (r>>3); bn = (r&7) + 8*q          (bijective over 512)
// Effect: each XCD owns 4 A-panels exclusively (A read from L3 once/XCD);
// resident window per XCD = 4bm x 8bn -> 12 unique panels (24MB) instead of
// ~18 (36MB); the 4 same-bn blocks are concurrent -> B panel (2MB) served
// from the 4MB per-XCD L2.  Staging demand on L3 drops ~3x.
// Everything else identical to R6 (swizzle 0-conflict, hazard discipline,
// vmcnt(4)/tile, 3 barriers/tile).
// ---------------------------------------------------------------------------
#define BM 256
#define BN 256
#define BK 64
#define MB_BLKS (TOKENS / BM)    // 32
#define NB_BLKS (DIM_OUT / BN)   // 16
#define NT      (DIM / BK)       // 64 K-tiles

#define SB0() __builtin_amdgcn_sched_barrier(0)
#define BAR() do { __builtin_amdgcn_s_barrier(); SB0(); } while (0)
#define VMWAIT_(n) asm volatile("s_waitcnt vmcnt(" #n ")" ::: "memory")
#define VMWAIT(n) VMWAIT_(n)

__global__ __launch_bounds__(512, 2) void gemm_kernel(
    const bf16_t* __restrict__ Xb, const bf16_t* __restrict__ Wt,
    const float* __restrict__ bias, float* __restrict__ C)
{
    __shared__ __align__(16) bf16_t sA[2][BM][BK];   // 64 KiB
    __shared__ __align__(16) bf16_t sB[2][BN][BK];   // 64 KiB

    // ---- XCD-local 2-D mapping (see header comment) ----
    int bid = blockIdx.x;
    int xcd = bid & 7;
    int j   = bid >> 3;              // 0..63 within XCD
    int qq  = j >> 5;                // 0..1
    int rr  = j & 31;                // 0..31
    int bm  = xcd * 4 + (rr >> 3);   // 0..31
    int bn  = (rr & 7) + 8 * qq;     // 0..15

    const int tid  = threadIdx.x;
    const int lane = tid & 63;
    const int wid  = tid >> 6;       // 0..7
    const int wr   = wid >> 2;       // 0..1  (M half: 128 rows)
    const int wc   = wid & 3;        // 0..3  (N quarter: 64 cols)

    // ---- staging constants (linear LDS dest, pre-swizzled global src) ----
    const int srow = tid >> 3;                       // 0..63
    const int scol = (tid & 7) * 8;                  // linear col (elems)
    const int koff = (((tid & 7) ^ ((tid >> 3) & 7)) * 8); // swizzled src col
    const bf16_t* Ag = Xb + (size_t)(bm * BM + srow) * DIM + koff;
    const bf16_t* Bg = Wt + (size_t)(bn * BN + srow) * DIM + koff;

#define STAGE_A(dd, kt) do { \
    const bf16_t* s_ = Ag + (size_t)(kt) * BK; \
    bf16_t* d_ = &sA[dd][srow][scol]; \
    gload_lds16(s_,                     d_); \
    gload_lds16(s_ + (size_t)64  * DIM, d_ + 64  * BK); \
    gload_lds16(s_ + (size_t)128 * DIM, d_ + 128 * BK); \
    gload_lds16(s_ + (size_t)192 * DIM, d_ + 192 * BK); \
} while (0)

#define STAGE_B(dd, kt) do { \
    const bf16_t* s_ = Bg + (size_t)(kt) * BK; \
    bf16_t* d_ = &sB[dd][srow][scol]; \
    gload_lds16(s_,                     d_); \
    gload_lds16(s_ + (size_t)64  * DIM, d_ + 64  * BK); \
    gload_lds16(s_ + (size_t)128 * DIM, d_ + 128 * BK); \
    gload_lds16(s_ + (size_t)192 * DIM, d_ + 192 * BK); \
} while (0)

    // ---- fragment-read constants (swizzled) ----
    const int q     = lane & 7;
    const int kslot = lane >> 4;                     // 0..3
    const int r15   = lane & 15;
    const int cK0   = ((kslot    ) ^ q) * 8;         // ks=0 col (elems)
    const int cK1   = ((kslot + 4) ^ q) * 8;         // ks=1 col (elems)
    const int arow0 = wr * 128 + r15;                // + m*16
    const int brow0 = wc * 64  + r15;                // + n*16

    f32x4 acc[8][4] = {};
    bfrag aLo[4][2], aHi[4][2], bLo[2][2], bHi[2][2];

#define READ_A4(dst, dd, mb) do { \
    _Pragma("unroll") \
    for (int m_ = 0; m_ < 4; ++m_) { \
        dst[m_][0] = *reinterpret_cast<const bfrag*>(&sA[dd][arow0 + (mb + m_) * 16][cK0]); \
        dst[m_][1] = *reinterpret_cast<const bfrag*>(&sA[dd][arow0 + (mb + m_) * 16][cK1]); \
    } \
} while (0)

#define READ_B2(dst, dd, nb) do { \
    _Pragma("unroll") \
    for (int n_ = 0; n_ < 2; ++n_) { \
        dst[n_][0] = *reinterpret_cast<const bfrag*>(&sB[dd][brow0 + (nb + n_) * 16][cK0]); \
        dst[n_][1] = *reinterpret_cast<const bfrag*>(&sB[dd][brow0 + (nb + n_) * 16][cK1]); \
    } \
} while (0)

#define MFMA_Q(Af, Bf, mb, nb) do { \
    __builtin_amdgcn_s_setprio(1); \
    _Pragma("unroll") \
    for (int m_ = 0; m_ < 4; ++m_) \
    _Pragma("unroll") \
    for (int n_ = 0; n_ < 2; ++n_) \
    _Pragma("unroll") \
    for (int ks_ = 0; ks_ < 2; ++ks_) \
        acc[mb + m_][nb + n_] = __builtin_amdgcn_mfma_f32_16x16x32_bf16( \
            Af[m_][ks_], Bf[n_][ks_], acc[mb + m_][nb + n_], 0, 0, 0); \
    __builtin_amdgcn_s_setprio(0); \
} while (0)

// One K-tile (buffer d), 3 intervals.  S: stage tile ktn -> buffer d.
// NEXTQ: read tile t+1's frags and do its Q00.  VM: vmcnt at J1.
#define TILE3(d, ktn, S, NEXTQ, VM) do { \
    /* J1 */ READ_A4(aHi, d, 4); if (S) STAGE_B(d, ktn); \
             SB0(); MFMA_Q(aLo, bHi, 0, 2); VMWAIT(VM); BAR(); \
    /* J2 */ if (NEXTQ) READ_A4(aLo, (d) ^ 1, 0); if (S) STAGE_A(d, ktn); \
             SB0(); MFMA_Q(aHi, bHi, 4, 2); BAR(); \
    /* M  */ MFMA_Q(aHi, bLo, 4, 0); \
             if (NEXTQ) { \
                 READ_B2(bLo, (d) ^ 1, 0); READ_B2(bHi, (d) ^ 1, 2); \
                 MFMA_Q(aLo, bLo, 0, 0); \
             } \
             BAR(); \
} while (0)

    // ---- prologue: tiles 0,1 staged; tile0's Q00 done here ----
    STAGE_A(0, 0); STAGE_B(0, 0);
    STAGE_B(1, 1); STAGE_A(1, 1);
    VMWAIT(8);          // tile 0 landed; tile 1's 8 loads stay in flight
    BAR();
    READ_A4(aLo, 0, 0); READ_B2(bLo, 0, 0); READ_B2(bHi, 0, 2);
    SB0();
    MFMA_Q(aLo, bLo, 0, 0);      // Q00(tile 0)
    BAR();                       // all waves' prologue reads issued before
                                 // any wave's J1 stage issues

    // ---- main loop: tiles 0..61 (31 iterations x 2), staging t+2 ----
    for (int it = 0; it < NT / 2 - 1; ++it) {
        int kt0 = 2 * it;
        TILE3(0, kt0 + 2, true, true, 4);
        TILE3(1, kt0 + 3, true, true, 4);
    }
    // ---- peeled tiles 62, 63 (fully staged; Q00(62) done at it=30's M) ----
    TILE3(0, 0, false, true, 0);   // VM(0): drain tile 63's loads
    TILE3(1, 0, false, false, 0);

    // ---- epilogue: D layout row=(lane>>4)*4+j, col=lane&15 ----
    int row0 = bm * BM + wr * 128 + (lane >> 4) * 4;
    int col0 = bn * BN + wc * 64 + r15;
#pragma unroll
    for (int n = 0; n < 4; ++n) {
        int c = col0 + n * 16;
        float bv = bias[c];
#pragma unroll
        for (int m = 0; m < 8; ++m) {
            int r = row0 + m * 16;
#pragma unroll
            for (int jj = 0; jj < 4; ++jj)
                C[(size_t)(r + jj) * DIM_OUT + c] = acc[m][n][jj] + bv;
        }
    }
}

// ---------------------------------------------------------------------------
extern "C" void kernel_launch(void* const* d_in, const int* in_sizes, int n_in,
                              void* d_out, int out_size, void* d_ws, size_t ws_size,
                              hipStream_t stream) {
    const float* x = (const float*)d_in[0];
    const float* A = (const float*)d_in[1];
    const float* B = (const float*)d_in[2];
    const float* W = (const float*)d_in[3];
    const float* b = (const float*)d_in[4];
    float* out = (float*)d_out;

    // workspace: xb (8192*4096 bf16 = 64MB) | Wt (4096*4096 bf16 = 32MB)
    bf16_t* xb = (bf16_t*)d_ws;
    bf16_t* Wt = (bf16_t*)((char*)d_ws + (size_t)TOKENS * DIM * 2);

    prep_kernel<<<CAST_BLOCKS + 2048, 256, 0, stream>>>(x, xb, W, A, B, Wt);
    gemm_kernel<<<MB_BLKS * NB_BLKS, 512, 0, stream>>>(xb, Wt, b, out);
}

// Round 13
// 327.483 us; speedup vs baseline: 6.2054x; 1.0005x over previous
//
#include <hip/hip_runtime.h>
#include <hip/hip_bf16.h>
#include <stdint.h>

// Problem constants (reference: LoRA adapter forward)
#define TOKENS   8192
#define DIM      4096
#define DIM_OUT  4096
#define LORA_R   16
#define LORA_SCALE 2.0f

typedef __bf16 bf16_t;
typedef __attribute__((ext_vector_type(8))) __bf16 bfrag;   // 8 bf16 = 4 VGPR (MFMA A/B frag)
typedef __attribute__((ext_vector_type(4))) float f32x4;    // MFMA C/D frag

// ---------------------------------------------------------------------------
// async global->LDS, 16B per lane (global_load_lds_dwordx4)
// ---------------------------------------------------------------------------
__device__ __forceinline__ void gload_lds16(const bf16_t* gsrc, bf16_t* ldst) {
    __builtin_amdgcn_global_load_lds(
        (const __attribute__((address_space(1))) uint32_t*)(const void*)gsrc,
        (__attribute__((address_space(3))) uint32_t*)(void*)ldst,
        16, 0, 0);
}

// ---------------------------------------------------------------------------
// Kernel 1: fused prep (R4/R6-validated form).
// Blocks [0,2048): cast x fp32->bf16.  Blocks [2048,4096): Weff.
// ---------------------------------------------------------------------------
#define CAST_BLOCKS 2048
__global__ void prep_kernel(const float* __restrict__ x, bf16_t* __restrict__ xb,
                            const float* __restrict__ W, const float* __restrict__ A,
                            const float* __restrict__ B, bf16_t* __restrict__ Wt) {
    if (blockIdx.x < CAST_BLOCKS) {
        const int total = TOKENS * DIM / 8;
        for (int i = blockIdx.x * blockDim.x + threadIdx.x; i < total;
             i += CAST_BLOCKS * 256) {
            const float4* p = reinterpret_cast<const float4*>(x + (size_t)i * 8);
            float4 v0 = p[0], v1 = p[1];
            union { bf16_t o[8]; uint4 u; } pk;
            pk.o[0] = (bf16_t)v0.x; pk.o[1] = (bf16_t)v0.y;
            pk.o[2] = (bf16_t)v0.z; pk.o[3] = (bf16_t)v0.w;
            pk.o[4] = (bf16_t)v1.x; pk.o[5] = (bf16_t)v1.y;
            pk.o[6] = (bf16_t)v1.z; pk.o[7] = (bf16_t)v1.w;
            *reinterpret_cast<uint4*>(xb + (size_t)i * 8) = pk.u;
        }
    } else {
        int idx = (blockIdx.x - CAST_BLOCKS) * blockDim.x + threadIdx.x;
        int k0 = (idx & 511) << 3;          // 512 k-groups of 8
        int n0 = (idx >> 9) << 2;           // 1024 n-groups of 4

        float bn[4][16];
#pragma unroll
        for (int r = 0; r < 16; ++r) {
            float4 bv = *reinterpret_cast<const float4*>(B + (size_t)r * DIM_OUT + n0);
            bn[0][r] = bv.x; bn[1][r] = bv.y; bn[2][r] = bv.z; bn[3][r] = bv.w;
        }
        float ab[4][8];
#pragma unroll
        for (int j = 0; j < 8; ++j) {
            const float4* ap = reinterpret_cast<const float4*>(A + (size_t)(k0 + j) * LORA_R);
            float4 a0 = ap[0], a1 = ap[1], a2 = ap[2], a3 = ap[3];
            float av[16] = {a0.x,a0.y,a0.z,a0.w,a1.x,a1.y,a1.z,a1.w,
                            a2.x,a2.y,a2.z,a2.w,a3.x,a3.y,a3.z,a3.w};
#pragma unroll
            for (int n = 0; n < 4; ++n) {
                float s = 0.f;
#pragma unroll
                for (int r = 0; r < 16; ++r) s += av[r] * bn[n][r];
                ab[n][j] = s;
            }
        }
#pragma unroll
        for (int n = 0; n < 4; ++n) {
            const float4* wp = reinterpret_cast<const float4*>(W + (size_t)(n0 + n) * DIM + k0);
            float4 w0 = wp[0], w1 = wp[1];
            float wv[8] = {w0.x,w0.y,w0.z,w0.w,w1.x,w1.y,w1.z,w1.w};
            union { bf16_t o[8]; uint4 u; } pk;
#pragma unroll
            for (int j = 0; j < 8; ++j) pk.o[j] = (bf16_t)(wv[j] + LORA_SCALE * ab[n][j]);
            *reinterpret_cast<uint4*>(Wt + (size_t)(n0 + n) * DIM + k0) = pk.u;
        }
    }
}

// ---------------------------------------------------------------------------
// Kernel 2: 256x256 GEMM, exact m201 8-phase template (T1+T2+T3+T4+T5),
// minimal sched fencing, uniform 1-half-tile-per-phase staging ledger.
// C[m][n] = sum_k Xb[m][k]*Wt[n][k] + bias[n]
// 512 thr = 8 waves (2M x 4N); per-wave 128x64 out = acc[8][4] 16x16 frags.
// LDS: dbuf0 (even tiles) + dbuf1 (odd tiles), each A 256x64 + B 256x64
// bf16 = 128 KiB total.  Swizzle (0 conflicts, R1-R3 measured).
//
// Iter j reads tiles u=2j (d0), v=u+1 (d1).  Phase = {ds_reads for THIS
// phase's MFMA; stage ONE half-tile (2 gloads); s_barrier; lgkmcnt(0)+SB0;
// setprio(1); 16 MFMA; setprio(0); s_barrier}.  Reads retire during barrier
// skew; staged writes land under later MFMA bursts (vmcnt once per 4 phases,
// never to 0).
//   P1: ds a0-3,b0-1(d0)[12]; stage A-H0(v)->d1   | MFMA m0-3 x n0-1
//   P2: ds b2-3(d0)[4];       stage A-H1(v)->d1   | MFMA m0-3 x n2-3
//   P3: ds a4-7(d0)[8];       stage B-H0(u+2)->d0 | MFMA m4-7 x n2-3
//   P4:                       stage B-H1(u+2)->d0 | MFMA m4-7 x n0-1; vmcnt(4)
//   P5: ds a0-3,b0-1(d1)[12]; stage A-H0(u+2)->d0 | MFMA m0-3 x n0-1
//   P6: ds b2-3(d1)[4];       stage A-H1(u+2)->d0 | MFMA m0-3 x n2-3
//   P7: ds a4-7(d1)[8];       stage B-H0(v+2)->d1 | MFMA m4-7 x n2-3
//   P8:                       stage B-H1(v+2)->d1 | MFMA m4-7 x n0-1; vmcnt(4)
// Ledger (2 gloads/half): @P4-end outstanding = B(v)[4]+A(v)[4]+B(u+2)[4]
//   -> vmcnt(4) retires B(v),A(v) exactly before P5 reads tile v.
// @P8-end outstanding = B(u+2)+A(u+2)+B(v+2) -> vmcnt(4) retires tile u+2
//   before next iter's P1.  2 halves always in flight (never drains).
// WAR per stage slot: target region's readers lgkm(0)-retired >=1 barrier
// before the stage issues (A(v)->d1.A: last reader A(v-2)@P7 prev iter;
// B(u+2)->d0.B: B(u)@P2; A(u+2)->d0.A: A(u)@P3; B(v+2)->d1.B: B(v)@P6).
// Last iter (u=62): P1,P2 still stage A(63); P3-P8 stages off; vmcnt(0)@P4.
// ---------------------------------------------------------------------------
#define BM 256
#define BN 256
#define BK 64
#define MB_BLKS (TOKENS / BM)    // 32
#define NB_BLKS (DIM_OUT / BN)   // 16
#define NT      (DIM / BK)       // 64 K-tiles

#define SB0() __builtin_amdgcn_sched_barrier(0)
#define VMWAIT_(n) asm volatile("s_waitcnt vmcnt(" #n ")" ::: "memory")
#define VMWAIT(n) VMWAIT_(n)

__global__ __launch_bounds__(512, 2) void gemm_kernel(
    const bf16_t* __restrict__ Xb, const bf16_t* __restrict__ Wt,
    const float* __restrict__ bias, float* __restrict__ C)
{
    __shared__ __align__(16) bf16_t sA[2][BM][BK];   // 64 KiB
    __shared__ __align__(16) bf16_t sB[2][BN][BK];   // 64 KiB

    // ---- XCD-local 2-D mapping (R11-validated: FETCH -33%) ----
    int bid = blockIdx.x;
    int xcd = bid & 7;
    int j   = bid >> 3;              // 0..63 within XCD
    int qq  = j >> 5;                // 0..1
    int rr  = j & 31;                // 0..31
    int bm  = xcd * 4 + (rr >> 3);   // 0..31
    int bn  = (rr & 7) + 8 * qq;     // 0..15

    const int tid  = threadIdx.x;
    const int lane = tid & 63;
    const int wid  = tid >> 6;       // 0..7
    const int wr   = wid >> 2;       // 0..1  (M half: 128 rows)
    const int wc   = wid & 3;        // 0..3  (N quarter: 64 cols)

    // ---- staging constants (linear LDS dest, pre-swizzled global src) ----
    const int srow = tid >> 3;                       // 0..63
    const int scol = (tid & 7) * 8;                  // linear col (elems)
    const int koff = (((tid & 7) ^ ((tid >> 3) & 7)) * 8); // swizzled src col
    const bf16_t* Ag = Xb + (size_t)(bm * BM + srow) * DIM + koff;
    const bf16_t* Bg = Wt + (size_t)(bn * BN + srow) * DIM + koff;

// stage half h (rows h*128 .. h*128+127) of A/B k-tile kt into dbuf dd
// (2 x gload_lds16 per thread = 16 KiB).  (srow+64)&7 == srow&7, so the
// swizzle key matches the verified pattern for both rows.
#define STAGE_A_H(dd, kt, h) do { \
    const bf16_t* s_ = Ag + (size_t)(kt) * BK + (size_t)((h) * 128) * DIM; \
    bf16_t* d_ = &sA[dd][(h) * 128 + srow][scol]; \
    gload_lds16(s_,                    d_); \
    gload_lds16(s_ + (size_t)64 * DIM, d_ + 64 * BK); \
} while (0)

#define STAGE_B_H(dd, kt, h) do { \
    const bf16_t* s_ = Bg + (size_t)(kt) * BK + (size_t)((h) * 128) * DIM; \
    bf16_t* d_ = &sB[dd][(h) * 128 + srow][scol]; \
    gload_lds16(s_,                    d_); \
    gload_lds16(s_ + (size_t)64 * DIM, d_ + 64 * BK); \
} while (0)

    // ---- fragment-read constants (swizzled) ----
    const int q     = lane & 7;
    const int kslot = lane >> 4;                     // 0..3
    const int r15   = lane & 15;
    const int cK0   = ((kslot    ) ^ q) * 8;         // ks=0 col (elems)
    const int cK1   = ((kslot + 4) ^ q) * 8;         // ks=1 col (elems)
    const int arow0 = wr * 128 + r15;                // + m*16
    const int brow0 = wc * 64  + r15;                // + n*16

    f32x4 acc[8][4] = {};
    bfrag a[4][2], bLo[2][2], bHi[2][2];

#define READ_A4(dd, mb) do { \
    _Pragma("unroll") \
    for (int m_ = 0; m_ < 4; ++m_) { \
        a[m_][0] = *reinterpret_cast<const bfrag*>(&sA[dd][arow0 + (mb + m_) * 16][cK0]); \
        a[m_][1] = *reinterpret_cast<const bfrag*>(&sA[dd][arow0 + (mb + m_) * 16][cK1]); \
    } \
} while (0)

#define READ_B2(dst, dd, nb) do { \
    _Pragma("unroll") \
    for (int n_ = 0; n_ < 2; ++n_) { \
        dst[n_][0] = *reinterpret_cast<const bfrag*>(&sB[dd][brow0 + (nb + n_) * 16][cK0]); \
        dst[n_][1] = *reinterpret_cast<const bfrag*>(&sB[dd][brow0 + (nb + n_) * 16][cK1]); \
    } \
} while (0)

// phase sync: barrier, then wait this phase's ds_reads, fence (rule #18)
#define PSYNC() do { \
    __builtin_amdgcn_s_barrier(); \
    asm volatile("s_waitcnt lgkmcnt(0)" ::: "memory"); \
    SB0(); \
} while (0)

#define MFMA_Q(Bf, mb, nb) do { \
    __builtin_amdgcn_s_setprio(1); \
    _Pragma("unroll") \
    for (int m_ = 0; m_ < 4; ++m_) \
    _Pragma("unroll") \
    for (int n_ = 0; n_ < 2; ++n_) \
    _Pragma("unroll") \
    for (int ks_ = 0; ks_ < 2; ++ks_) \
        acc[mb + m_][nb + n_] = __builtin_amdgcn_mfma_f32_16x16x32_bf16( \
            a[m_][ks_], Bf[n_][ks_], acc[mb + m_][nb + n_], 0, 0, 0); \
    __builtin_amdgcn_s_setprio(0); \
} while (0)

#define EBAR() __builtin_amdgcn_s_barrier()

// 4 phases for one K-tile read from dbuf d.  kAv: A-halves of tile kAv -> d^1
// (phases 1,2; always on).  kS: B/A halves of tile kS staged per slots
// (P3,P4 here; P5,P6 of the pair stage A(kS) -- see TILEPAIR).  VM at P4.
#define TILEPAIR(u, S, VMn) do { \
    /* P1 */ READ_A4(0, 0); READ_B2(bLo, 0, 0); STAGE_A_H(1, (u) + 1, 0); \
             PSYNC(); MFMA_Q(bLo, 0, 0); EBAR(); \
    /* P2 */ READ_B2(bHi, 0, 2); STAGE_A_H(1, (u) + 1, 1); \
             PSYNC(); MFMA_Q(bHi, 0, 2); EBAR(); \
    /* P3 */ READ_A4(0, 4); if (S) STAGE_B_H(0, (u) + 2, 0); \
             PSYNC(); MFMA_Q(bHi, 4, 2); EBAR(); \
    /* P4 */ if (S) STAGE_B_H(0, (u) + 2, 1); \
             __builtin_amdgcn_s_barrier(); \
             MFMA_Q(bLo, 4, 0); VMWAIT(VMn); EBAR(); \
    /* P5 */ READ_A4(1, 0); READ_B2(bLo, 1, 0); if (S) STAGE_A_H(0, (u) + 2, 0); \
             PSYNC(); MFMA_Q(bLo, 0, 0); EBAR(); \
    /* P6 */ READ_B2(bHi, 1, 2); if (S) STAGE_A_H(0, (u) + 2, 1); \
             PSYNC(); MFMA_Q(bHi, 0, 2); EBAR(); \
    /* P7 */ READ_A4(1, 4); if (S) STAGE_B_H(1, (u) + 3, 0); \
             PSYNC(); MFMA_Q(bHi, 4, 2); EBAR(); \
    /* P8 */ if (S) STAGE_B_H(1, (u) + 3, 1); \
             __builtin_amdgcn_s_barrier(); \
             MFMA_Q(bLo, 4, 0); VMWAIT(0); EBAR(); \
} while (0)

    // ---- prologue: tile0 fully -> d0 (8 loads); B(1) -> d1 (4 loads) ----
    STAGE_A_H(0, 0, 0); STAGE_A_H(0, 0, 1);
    STAGE_B_H(0, 0, 0); STAGE_B_H(0, 0, 1);
    STAGE_B_H(1, 1, 0); STAGE_B_H(1, 1, 1);
    VMWAIT(4);          // tile0's 8 landed; B(1)'s 4 stay in flight
    EBAR();

    // ---- main loop: iters 0..30 read tiles (2j, 2j+1), stage (2j+2, 2j+3).
    // P8 uses vmcnt(4) in steady state -- expressed via the macro's VMWAIT(0)
    // replaced below: we inline the steady-state pair with VM=4 at P4 and
    // patch P8 by splitting the last iteration out.
    for (int it = 0; it < NT / 2 - 1; ++it) {
        int u = 2 * it;
        /* P1 */ READ_A4(0, 0); READ_B2(bLo, 0, 0); STAGE_A_H(1, u + 1, 0);
                 PSYNC(); MFMA_Q(bLo, 0, 0); EBAR();
        /* P2 */ READ_B2(bHi, 0, 2); STAGE_A_H(1, u + 1, 1);
                 PSYNC(); MFMA_Q(bHi, 0, 2); EBAR();
        /* P3 */ READ_A4(0, 4); STAGE_B_H(0, u + 2, 0);
                 PSYNC(); MFMA_Q(bHi, 4, 2); EBAR();
        /* P4 */ STAGE_B_H(0, u + 2, 1);
                 __builtin_amdgcn_s_barrier();
                 MFMA_Q(bLo, 4, 0); VMWAIT(4); EBAR();
        /* P5 */ READ_A4(1, 0); READ_B2(bLo, 1, 0); STAGE_A_H(0, u + 2, 0);
                 PSYNC(); MFMA_Q(bLo, 0, 0); EBAR();
        /* P6 */ READ_B2(bHi, 1, 2); STAGE_A_H(0, u + 2, 1);
                 PSYNC(); MFMA_Q(bHi, 0, 2); EBAR();
        /* P7 */ READ_A4(1, 4); STAGE_B_H(1, u + 3, 0);
                 PSYNC(); MFMA_Q(bHi, 4, 2); EBAR();
        /* P8 */ STAGE_B_H(1, u + 3, 1);
                 __builtin_amdgcn_s_barrier();
                 MFMA_Q(bLo, 4, 0); VMWAIT(4); EBAR();
    }
    // ---- last iter (tiles 62,63): P1,P2 still stage A(63); rest off ----
    /* P1 */ READ_A4(0, 0); READ_B2(bLo, 0, 0); STAGE_A_H(1, 63, 0);
             PSYNC(); MFMA_Q(bLo, 0, 0); EBAR();
    /* P2 */ READ_B2(bHi, 0, 2); STAGE_A_H(1, 63, 1);
             PSYNC(); MFMA_Q(bHi, 0, 2); EBAR();
    /* P3 */ READ_A4(0, 4);
             PSYNC(); MFMA_Q(bHi, 4, 2); EBAR();
    /* P4 */ __builtin_amdgcn_s_barrier();
             MFMA_Q(bLo, 4, 0); VMWAIT(0); EBAR();   // drain: A(63),B(63) land
    /* P5 */ READ_A4(1, 0); READ_B2(bLo, 1, 0);
             PSYNC(); MFMA_Q(bLo, 0, 0); EBAR();
    /* P6 */ READ_B2(bHi, 1, 2);
             PSYNC(); MFMA_Q(bHi, 0, 2); EBAR();
    /* P7 */ READ_A4(1, 4);
             PSYNC(); MFMA_Q(bHi, 4, 2); EBAR();
    /* P8 */ MFMA_Q(bLo, 4, 0);

    // ---- epilogue: D layout row=(lane>>4)*4+j, col=lane&15 ----
    int row0 = bm * BM + wr * 128 + (lane >> 4) * 4;
    int col0 = bn * BN + wc * 64 + r15;
#pragma unroll
    for (int n = 0; n < 4; ++n) {
        int c = col0 + n * 16;
        float bv = bias[c];
#pragma unroll
        for (int m = 0; m < 8; ++m) {
            int r = row0 + m * 16;
#pragma unroll
            for (int jj = 0; jj < 4; ++jj)
                C[(size_t)(r + jj) * DIM_OUT + c] = acc[m][n][jj] + bv;
        }
    }
}

// ---------------------------------------------------------------------------
extern "C" void kernel_launch(void* const* d_in, const int* in_sizes, int n_in,
                              void* d_out, int out_size, void* d_ws, size_t ws_size,
                              hipStream_t stream) {
    const float* x = (const float*)d_in[0];
    const float* A = (const float*)d_in[1];
    const float* B = (const float*)d_in[2];
    const float* W = (const float*)d_in[3];
    const float* b = (const float*)d_in[4];
    float* out = (float*)d_out;

    // workspace: xb (8192*4096 bf16 = 64MB) | Wt (4096*4096 bf16 = 32MB)
    bf16_t* xb = (bf16_t*)d_ws;
    bf16_t* Wt = (bf16_t*)((char*)d_ws + (size_t)TOKENS * DIM * 2);

    prep_kernel<<<CAST_BLOCKS + 2048, 256, 0, stream>>>(x, xb, W, A, B, Wt);
    gemm_kernel<<<MB_BLKS * NB_BLKS, 512, 0, stream>>>(xb, Wt, b, out);
}